// Round 11
// baseline (298.353 us; speedup 1.0000x reference)
//
#include <hip/hip_runtime.h>
#include <stdint.h>

// B=4, S=2048, D=1024, H=16, Hd=64, M=8192.
// Pipeline: prep (cast x -> bf16 + merged W^T casts, ONE dispatch); merged
// QKV GEMM (128^2, fragment-major LDS, XCD-chunked; Q pre-scaled by log2e/8;
// V written TRANSPOSED [bh][hd][s] from the epilogue); flash attn (S^T =
// K@Q^T key-permutation trick); O-projection GEMM (row-major 128^2, fp32).
// Ledger: R2 XCD decode cuts attn FETCH 139->24.6MB. R3 setprio hurts
// lockstep attn. R4-R8 256^2 QKV pinned ~80-95us (K=1024, 1.5 dispatch
// rounds). R5 frag-major LDS: conflicts 4.7M->0 (mechanics proven).
// R10: V^T fused into QKV epilogue, transpose_v deleted -> 268.6 (best).
//   Dispatch-sum ledger shows ~55us of inter-dispatch gap (~10us/dispatch).
// R11: (a) QKV -> fragment-major LDS (kill its 6.29M conflict cyc = 12% of
//   dispatch); O-proj left row-major to isolate the R5 frag-major mystery.
//   (b) cast_x + transpose_cast4 merged into one prep dispatch (-1 gap).

typedef float f32x4 __attribute__((ext_vector_type(4)));
typedef __bf16 bf16x4 __attribute__((ext_vector_type(4)));
typedef __bf16 bf16x8 __attribute__((ext_vector_type(8)));
typedef uint32_t u32x4 __attribute__((ext_vector_type(4)));

#define MFMA16(a, b, c) __builtin_amdgcn_mfma_f32_16x16x32_bf16((a), (b), (c), 0, 0, 0)

// Q pre-scale: log2(e)/8 so attn does p = exp2(Q'.K) = e^{QK/8} (unnormalized)
#define QSCALE 0.1803368801111204f

__device__ __forceinline__ unsigned short f2bf(float f) {
  union { float f; uint32_t u; } c; c.f = f;
  uint32_t u = c.u;
  return (unsigned short)((u + 0x7fffu + ((u >> 16) & 1u)) >> 16);  // RNE
}

// ---------------------------------------------------------------- prep
// blocks [0,8192): cast x (fp32 -> bf16, float4/ushort4 vectorized).
// blocks [8192,12288): W^T casts — 4 weights [k][n] fp32 -> Wt [n][k] bf16,
// 32x32 LDS tile per block (1024 blocks per weight).
__global__ __launch_bounds__(256) void prep_kernel(const float* __restrict__ x,
                                                   unsigned short* __restrict__ xb,
                                                   const float* __restrict__ W0,
                                                   const float* __restrict__ W1,
                                                   const float* __restrict__ W2,
                                                   const float* __restrict__ W3,
                                                   unsigned short* __restrict__ Wt) {
  __shared__ float tile[32][33];
  const int id = blockIdx.x;
  const int tid = threadIdx.x;
  if (id < 8192) {
    int i = id * 256 + tid;  // exactly 2097152 float4s
    float4 v = ((const float4*)x)[i];
    ushort4 o;
    o.x = f2bf(v.x); o.y = f2bf(v.y); o.z = f2bf(v.z); o.w = f2bf(v.w);
    ((ushort4*)xb)[i] = o;
  } else {
    const int t = id - 8192;
    const int z = t >> 10, r = t & 1023;
    const int k0 = (r >> 5) * 32, n0 = (r & 31) * 32;
    const float* W = (z == 0) ? W0 : (z == 1) ? W1 : (z == 2) ? W2 : W3;
    unsigned short* dst = Wt + (size_t)z * 1048576;
    const int tx = tid & 31, ty = tid >> 5;  // 32 x 8
#pragma unroll
    for (int i = 0; i < 32; i += 8)
      tile[ty + i][tx] = W[(size_t)(k0 + ty + i) * 1024 + n0 + tx];
    __syncthreads();
#pragma unroll
    for (int i = 0; i < 32; i += 8)
      dst[(size_t)(n0 + ty + i) * 1024 + k0 + tx] = f2bf(tile[tx][ty + i]);
  }
}

// ---------------------------------------------------------------- QKV GEMM 128^2, fragment-major
// A [8192][1024] bf16, Bt [3072][1024]. out = QKV bf16 base (Q,K scatter to
// [b,h,s,hd]; Q scaled by QSCALE); mb==2 (V) written TRANSPOSED to
// vtg[bh][hd][s] as 8B ushort4. grid 1536 flat, XCD-chunked decode.
// Fragment-major LDS (R5-proven, 0 conflicts): msub m (16 rows) occupies
// 1024B; chunk (m*64 + quad*16 + l16)*16B holds row m*16+l16, k quad*8..+8.
// Staged by lane order (lane = quad*16+l16 matches chunk order); frag read =
// base + lane*16 -> 1024 sequential bytes.
__global__ __launch_bounds__(256) void gemm128_qkv(const unsigned short* __restrict__ A,
                                                   const unsigned short* __restrict__ Bt,
                                                   const float* __restrict__ b0,
                                                   const float* __restrict__ b1,
                                                   const float* __restrict__ b2,
                                                   unsigned short* __restrict__ out,
                                                   unsigned short* __restrict__ vtg) {
  __shared__ unsigned short sm[8192];  // A 8KB | B 8KB
  auto lds3 = (__attribute__((address_space(3))) char*)sm;

  const int tid = threadIdx.x;
  const int wave = tid >> 6, lane = tid & 63, quad = lane >> 4, l16 = lane & 15;
  const int wm = wave >> 1, wn = wave & 1;

  const int id = blockIdx.x;
  const int nid = id >> 3;
  const int by = (id & 7) * 8 + (nid & 7);
  const int bx = nid >> 3;
  const int bm = by * 128, bn = bx * 128;

  const unsigned short* gA0 = A + (size_t)(bm + wave * 16 + l16) * 1024 + quad * 8;
  const unsigned short* gA1 = gA0 + (size_t)64 * 1024;
  const unsigned short* gB0 = Bt + (size_t)(bn + wave * 16 + l16) * 1024 + quad * 8;
  const unsigned short* gB1 = gB0 + (size_t)64 * 1024;
  const int ldw = wave * 1024;

  f32x4 acc[4][4] = {};

  for (int k0 = 0; k0 < 1024; k0 += 32) {
    __builtin_amdgcn_global_load_lds(
        (const __attribute__((address_space(1))) void*)(gA0 + k0),
        (__attribute__((address_space(3))) void*)(lds3 + ldw), 16, 0, 0);
    __builtin_amdgcn_global_load_lds(
        (const __attribute__((address_space(1))) void*)(gA1 + k0),
        (__attribute__((address_space(3))) void*)(lds3 + 4096 + ldw), 16, 0, 0);
    __builtin_amdgcn_global_load_lds(
        (const __attribute__((address_space(1))) void*)(gB0 + k0),
        (__attribute__((address_space(3))) void*)(lds3 + 8192 + ldw), 16, 0, 0);
    __builtin_amdgcn_global_load_lds(
        (const __attribute__((address_space(1))) void*)(gB1 + k0),
        (__attribute__((address_space(3))) void*)(lds3 + 12288 + ldw), 16, 0, 0);
    __syncthreads();

    bf16x8 af[4], bfv[4];
#pragma unroll
    for (int i = 0; i < 4; ++i)
      af[i] = *(const bf16x8*)(sm + ((wm * 4 + i) << 9) + (lane << 3));
#pragma unroll
    for (int n = 0; n < 4; ++n)
      bfv[n] = *(const bf16x8*)(sm + 4096 + ((wn * 4 + n) << 9) + (lane << 3));
#pragma unroll
    for (int i = 0; i < 4; ++i)
#pragma unroll
      for (int n = 0; n < 4; ++n)
        acc[i][n] = MFMA16(af[i], bfv[n], acc[i][n]);
    __syncthreads();
  }

  // epilogue: C/D layout col=lane&15, row=quad*4+reg
  const int mb = bn >> 10;  // block never straddles: 1024 % 128 == 0
  const float* bias = (mb == 0) ? b0 : (mb == 1 ? b1 : b2);
  const float scale = (mb == 0) ? QSCALE : 1.0f;
  unsigned short* oq = out + (size_t)mb * 8388608u;

#pragma unroll
  for (int i = 0; i < 4; ++i) {
    const int row0 = bm + wm * 64 + i * 16 + quad * 4;
#pragma unroll
    for (int n = 0; n < 4; ++n) {
      const int col = bn + wn * 64 + n * 16 + l16;
      const int cl = col & 1023;
      const float bv = bias[cl];
      if (mb == 2) {
        // V^T: vtg[(b*16+h)][hd][s], 4 consecutive s per thread -> 8B store
        const int h = cl >> 6, hd = cl & 63;
        const int b = row0 >> 11, s0v = row0 & 2047;
        ushort4 pk;
        pk.x = f2bf(acc[i][n][0] + bv);
        pk.y = f2bf(acc[i][n][1] + bv);
        pk.z = f2bf(acc[i][n][2] + bv);
        pk.w = f2bf(acc[i][n][3] + bv);
        *(ushort4*)(vtg + (size_t)(b * 16 + h) * 131072 + (size_t)hd * 2048 + s0v) = pk;
      } else {
#pragma unroll
        for (int r = 0; r < 4; ++r) {
          float v = (acc[i][n][r] + bv) * scale;
          int rr = row0 + r;
          int b = rr >> 11, s = rr & 2047;
          int h = cl >> 6, hd = cl & 63;
          oq[((size_t)(b * 16 + h) * 2048 + s) * 64 + hd] = f2bf(v);
        }
      }
    }
  }
}

// ---------------------------------------------------------------- O-proj GEMM (R3-proven row-major)
// out fp32 [8192][1024], bias b0. grid 512 flat, XCD-chunked decode.
__global__ __launch_bounds__(256) void gemm128_oproj(const unsigned short* __restrict__ A,
                                                     const unsigned short* __restrict__ Bt,
                                                     const float* __restrict__ b0,
                                                     float* __restrict__ out) {
  constexpr int Kd = 1024;
  __shared__ unsigned short sm[128 * 32 + 32 * 128];
  unsigned short* As = sm;
  unsigned short* Bs = sm + 128 * 32;
  auto lds3 = (__attribute__((address_space(3))) char*)sm;

  const int tid = threadIdx.x;
  const int wave = tid >> 6, lane = tid & 63, quad = lane >> 4, l16 = lane & 15;
  const int wm = wave >> 1, wn = wave & 1;

  const int id = blockIdx.x;
  const int nid = id >> 3;
  const int by = (id & 7) * 8 + (nid & 7);
  const int bx = nid >> 3;
  const int bm = by * 128, bn = bx * 128;

  f32x4 acc[4][4] = {};

  for (int k0 = 0; k0 < Kd; k0 += 32) {
#pragma unroll
    for (int j = 0; j < 2; ++j) {
      int i = (wave * 2 + j) * 64 + lane;  // 16B-chunk index 0..511
      const unsigned short* ga = A + (size_t)(bm + (i >> 2)) * Kd + k0 + (i & 3) * 8;
      __builtin_amdgcn_global_load_lds(
          (const __attribute__((address_space(1))) void*)ga,
          (__attribute__((address_space(3))) void*)(lds3 + (size_t)(wave * 2 + j) * 1024),
          16, 0, 0);
      const unsigned short* gb = Bt + (size_t)(bn + (i >> 2)) * Kd + k0 + (i & 3) * 8;
      __builtin_amdgcn_global_load_lds(
          (const __attribute__((address_space(1))) void*)gb,
          (__attribute__((address_space(3))) void*)(lds3 + 8192 + (size_t)(wave * 2 + j) * 1024),
          16, 0, 0);
    }
    __syncthreads();

    bf16x8 af[4], bfv[4];
#pragma unroll
    for (int i = 0; i < 4; ++i)
      af[i] = *(const bf16x8*)(As + (wm * 64 + i * 16 + l16) * 32 + quad * 8);
#pragma unroll
    for (int n = 0; n < 4; ++n)
      bfv[n] = *(const bf16x8*)(Bs + (wn * 64 + n * 16 + l16) * 32 + quad * 8);
#pragma unroll
    for (int i = 0; i < 4; ++i)
#pragma unroll
      for (int n = 0; n < 4; ++n)
        acc[i][n] = MFMA16(af[i], bfv[n], acc[i][n]);
    __syncthreads();
  }

  // epilogue: C/D layout col=lane&15, row=quad*4+reg
#pragma unroll
  for (int i = 0; i < 4; ++i) {
    const int row0 = bm + wm * 64 + i * 16 + quad * 4;
#pragma unroll
    for (int n = 0; n < 4; ++n) {
      const int col = bn + wn * 64 + n * 16 + l16;
      const float bv = b0[col & 1023];
#pragma unroll
      for (int r = 0; r < 4; ++r)
        out[(size_t)(row0 + r) * 1024 + col] = acc[i][n][r] + bv;
    }
  }
}

// ---------------------------------------------------------------- flash attention
// Q pre-scaled. 512 flat blocks; block = (b,h) x 256 q-rows; wave = 64 q-rows
// (4 subtiles). XCD-grouped decode: bh = (id&7)*8 + ((id>>3)>>3) so all 8
// q-blocks of a head (and 8 whole heads) land on one XCD -> K/Vt L2-resident
// (proven R2/R3: FETCH 139 -> 25.7 MB). No setprio: lockstep loop (m190/R3).
// S^T = K(A) @ Q^T(B): C-layout puts col=l16=qrow, so each lane's 16 exp2'd
// scores (keys quad*4+r per subtile) form PV A-frags directly under the key
// permutation sigma(q*8+j) = st*32 + (j>>2)*16 + q*4 + (j&3); V B-frags use
// the same sigma (two contiguous b64 chunks from the Vt tile). No P in LDS.
__global__ __launch_bounds__(256, 2) void attn_kernel(const unsigned short* __restrict__ Q,
                                                      const unsigned short* __restrict__ K,
                                                      const unsigned short* __restrict__ Vt,
                                                      unsigned short* __restrict__ ctx) {
  const int tid = threadIdx.x;
  const int wave = tid >> 6, lane = tid & 63, quad = lane >> 4, l16 = lane & 15;

  const int id = blockIdx.x;
  const int bh = (id & 7) * 8 + ((id >> 3) >> 3);  // 8 heads per XCD
  const int qx = (id >> 3) & 7;

  // stride 72 ushorts = 36 dwords == 4 mod 32 -> conflict-free-ish frag reads
  // double buffer: [buf][Ks 64*72 | Vts 64*72]
  __shared__ unsigned short sm[2][2 * 64 * 72];

  const size_t hb = (size_t)bh * 131072;
  const int q0 = qx * 256 + wave * 64;

  // Q B-frags: B[k=hd][n=qrow]: lane l16 = qrow, k = quad*8+j (+32*st)
  bf16x8 qf[4][2];
#pragma unroll
  for (int qt = 0; qt < 4; ++qt)
#pragma unroll
    for (int st = 0; st < 2; ++st)
      qf[qt][st] = *(const bf16x8*)(Q + hb + (size_t)(q0 + qt * 16 + l16) * 64 + st * 32 + quad * 8);

  f32x4 o[4][4] = {};
  float lacc[4] = {0.f, 0.f, 0.f, 0.f};

  // staging: 4 x 16B chunks/thread (2 K rows-of-keys + 2 Vt rows-of-hd)
  const int c0 = tid, c1 = tid + 256;
  const unsigned short* gK0 = K + hb + (size_t)(c0 >> 3) * 64 + (c0 & 7) * 8;
  const unsigned short* gK1 = K + hb + (size_t)(c1 >> 3) * 64 + (c1 & 7) * 8;
  const unsigned short* gV0 = Vt + hb + (size_t)(c0 >> 3) * 2048 + (c0 & 7) * 8;
  const unsigned short* gV1 = Vt + hb + (size_t)(c1 >> 3) * 2048 + (c1 & 7) * 8;
  const int sKo = (c0 >> 3) * 72 + (c0 & 7) * 8;
  const int sKo1 = (c1 >> 3) * 72 + (c1 & 7) * 8;

  u32x4 pk0 = *(const u32x4*)gK0, pk1 = *(const u32x4*)gK1;
  u32x4 pv0 = *(const u32x4*)gV0, pv1 = *(const u32x4*)gV1;
  {
    unsigned short* s0b = sm[0];
    *(u32x4*)(s0b + sKo) = pk0; *(u32x4*)(s0b + sKo1) = pk1;
    *(u32x4*)(s0b + 4608 + sKo) = pv0; *(u32x4*)(s0b + 4608 + sKo1) = pv1;
  }
  __syncthreads();

  for (int kb = 0; kb < 2048; kb += 64) {
    const int cur = (kb >> 6) & 1;
    const bool more = (kb + 64) < 2048;
    if (more) {
      pk0 = *(const u32x4*)(gK0 + (size_t)(kb + 64) * 64);
      pk1 = *(const u32x4*)(gK1 + (size_t)(kb + 64) * 64);
      pv0 = *(const u32x4*)(gV0 + kb + 64);
      pv1 = *(const u32x4*)(gV1 + kb + 64);
    }
    const unsigned short* Ks = sm[cur];
    const unsigned short* Vts = sm[cur] + 4608;

    // K A-frags: A[m=key][k=hd]: lane l16 = key (per subtile ks), contiguous hd
    bf16x8 kf[4][2];
#pragma unroll
    for (int ks = 0; ks < 4; ++ks)
#pragma unroll
      for (int st = 0; st < 2; ++st)
        kf[ks][st] = *(const bf16x8*)(Ks + (ks * 16 + l16) * 72 + st * 32 + quad * 8);

    // V B-frags under sigma: two b64 chunks (keys st*32+quad*4+{0..3}, +16)
    bf16x8 vf[4][2];
#pragma unroll
    for (int os = 0; os < 4; ++os)
#pragma unroll
      for (int st = 0; st < 2; ++st) {
        const unsigned short* rb = Vts + (os * 16 + l16) * 72 + st * 32 + quad * 4;
        bf16x4 a = *(const bf16x4*)rb;
        bf16x4 b2 = *(const bf16x4*)(rb + 16);
        vf[os][st] = __builtin_shufflevector(a, b2, 0, 1, 2, 3, 4, 5, 6, 7);
      }

#pragma unroll
    for (int qt = 0; qt < 4; ++qt) {
      // S^T tiles: rows = keys (quad*4+r), cols = qrows (l16)
      f32x4 sc[4];
#pragma unroll
      for (int ks = 0; ks < 4; ++ks) {
        f32x4 a = {0.f, 0.f, 0.f, 0.f};
        a = MFMA16(kf[ks][0], qf[qt][0], a);
        a = MFMA16(kf[ks][1], qf[qt][1], a);
        sc[ks] = a;
      }
      // exp2 -> P A-frags in-register; per-lane l partials (all for qrow l16)
      bf16x8 pf[2];
      float ls = 0.f;
#pragma unroll
      for (int ks = 0; ks < 4; ++ks)
#pragma unroll
        for (int r = 0; r < 4; ++r) {
          float p = __builtin_amdgcn_exp2f(sc[ks][r]);
          ls += p;
          pf[ks >> 1][(ks & 1) * 4 + r] = (__bf16)p;
        }
      lacc[qt] += ls;
#pragma unroll
      for (int st = 0; st < 2; ++st)
#pragma unroll
        for (int os = 0; os < 4; ++os)
          o[qt][os] = MFMA16(pf[st], vf[os][st], o[qt][os]);
    }

    if (more) {
      unsigned short* sn = sm[cur ^ 1];
      *(u32x4*)(sn + sKo) = pk0; *(u32x4*)(sn + sKo1) = pk1;
      *(u32x4*)(sn + 4608 + sKo) = pv0; *(u32x4*)(sn + 4608 + sKo1) = pv1;
    }
    __syncthreads();
  }

  // finalize: reduce l across quads (lane's l16 = qrow), redistribute to
  // C-layout rows (quad*4+r), normalize, store.
  const int b = bh >> 4, h = bh & 15;
#pragma unroll
  for (int qt = 0; qt < 4; ++qt) {
    float l = lacc[qt];
    l += __shfl_xor(l, 16, 64);
    l += __shfl_xor(l, 32, 64);
#pragma unroll
    for (int r = 0; r < 4; ++r) {
      float lr = __shfl(l, quad * 4 + r, 16);
      float inv = 1.0f / lr;
      int s = q0 + qt * 16 + quad * 4 + r;
#pragma unroll
      for (int os = 0; os < 4; ++os)
        ctx[((size_t)(b * 2048 + s)) * 1024 + h * 64 + os * 16 + l16] = f2bf(o[qt][os][r] * inv);
    }
  }
}

// ---------------------------------------------------------------- launch
extern "C" void kernel_launch(void* const* d_in, const int* in_sizes, int n_in,
                              void* d_out, int out_size, void* d_ws, size_t ws_size,
                              hipStream_t stream) {
  const float* x  = (const float*)d_in[0];
  const float* Wq = (const float*)d_in[1];
  const float* bq = (const float*)d_in[2];
  const float* Wk = (const float*)d_in[3];
  const float* bk = (const float*)d_in[4];
  const float* Wv = (const float*)d_in[5];
  const float* bv = (const float*)d_in[6];
  const float* Wo = (const float*)d_in[7];
  const float* bo = (const float*)d_in[8];

  unsigned short* ws = (unsigned short*)d_ws;
  unsigned short* xb    = ws;                    // 8388608  A input; attn out after QKV
  unsigned short* Wtall = ws + 8388608;          // 4*1048576 (Wq^T|Wk^T|Wv^T|Wo^T)
  unsigned short* Wot   = Wtall + 3145728;
  unsigned short* Qb    = Wtall + 4194304;       // 8388608  [bh][s][hd], pre-scaled
  unsigned short* Kb    = Qb + 8388608;          // 8388608  [bh][s][hd]
  unsigned short* VtG   = Kb + 8388608;          // 8388608  [bh][hd][s] (written by QKV epilogue)
  unsigned short* Cb    = xb;                    // alias: xb dead after QKV GEMM

  prep_kernel<<<dim3(12288), 256, 0, stream>>>(x, xb, Wq, Wk, Wv, Wo, Wtall);
  gemm128_qkv<<<dim3(1536), 256, 0, stream>>>(xb, Wtall, bq, bk, bv, Qb, VtG);
  attn_kernel<<<dim3(512), 256, 0, stream>>>(Qb, Kb, VtG, Cb);
  gemm128_oproj<<<dim3(512), 256, 0, stream>>>(Cb, Wot, bo, (float*)d_out);
}

// Round 12
// 270.667 us; speedup vs baseline: 1.1023x; 1.1023x over previous
//
#include <hip/hip_runtime.h>
#include <stdint.h>

// B=4, S=2048, D=1024, H=16, Hd=64, M=8192.
// Pipeline: prep (cast x -> bf16 + merged W^T casts, ONE dispatch); merged
// QKV GEMM (128^2 row-major tile, XCD-chunked; Q pre-scaled by log2e/8;
// V written TRANSPOSED [bh][hd][s] from the epilogue); flash attn (S^T =
// K@Q^T key-permutation trick); O-projection GEMM (row-major 128^2, fp32).
// Ledger: R2 XCD decode cuts attn FETCH 139->24.6MB. R3 setprio hurts
// lockstep attn. R4-R8: 256^2 QKV pinned ~80-95us regardless of schedule.
// R10: V^T fused into QKV epilogue -> 268.6 (best). ~55us inter-dispatch gap.
// R11: frag-major LDS on 128^2: conflicts 6.29M->0 BUT dur 85.3->111.9 —
//   with global_load_lds, read-sequential LDS forces lane-permuted global
//   reads (2048B-apart consecutive lanes) -> coalescing loss >> conflict
//   cost. On 2-phase structures conflicts are off critical path (T2 regime
//   gate). Resolves R5's O-proj mystery. Row-major + 8-way conflict is the
//   local optimum for this tile.
// R12: QKV reverted to R10 row-major; prep-merge kept (R11 residual ~ noise;
//   -1 dispatch). Best-known recombination.

typedef float f32x4 __attribute__((ext_vector_type(4)));
typedef __bf16 bf16x4 __attribute__((ext_vector_type(4)));
typedef __bf16 bf16x8 __attribute__((ext_vector_type(8)));
typedef uint32_t u32x4 __attribute__((ext_vector_type(4)));

#define MFMA16(a, b, c) __builtin_amdgcn_mfma_f32_16x16x32_bf16((a), (b), (c), 0, 0, 0)

// Q pre-scale: log2(e)/8 so attn does p = exp2(Q'.K) = e^{QK/8} (unnormalized)
#define QSCALE 0.1803368801111204f

__device__ __forceinline__ unsigned short f2bf(float f) {
  union { float f; uint32_t u; } c; c.f = f;
  uint32_t u = c.u;
  return (unsigned short)((u + 0x7fffu + ((u >> 16) & 1u)) >> 16);  // RNE
}

// ---------------------------------------------------------------- prep
// blocks [0,8192): cast x (fp32 -> bf16, float4/ushort4 vectorized).
// blocks [8192,12288): W^T casts — 4 weights [k][n] fp32 -> Wt [n][k] bf16,
// 32x32 LDS tile per block (1024 blocks per weight).
__global__ __launch_bounds__(256) void prep_kernel(const float* __restrict__ x,
                                                   unsigned short* __restrict__ xb,
                                                   const float* __restrict__ W0,
                                                   const float* __restrict__ W1,
                                                   const float* __restrict__ W2,
                                                   const float* __restrict__ W3,
                                                   unsigned short* __restrict__ Wt) {
  __shared__ float tile[32][33];
  const int id = blockIdx.x;
  const int tid = threadIdx.x;
  if (id < 8192) {
    int i = id * 256 + tid;  // exactly 2097152 float4s
    float4 v = ((const float4*)x)[i];
    ushort4 o;
    o.x = f2bf(v.x); o.y = f2bf(v.y); o.z = f2bf(v.z); o.w = f2bf(v.w);
    ((ushort4*)xb)[i] = o;
  } else {
    const int t = id - 8192;
    const int z = t >> 10, r = t & 1023;
    const int k0 = (r >> 5) * 32, n0 = (r & 31) * 32;
    const float* W = (z == 0) ? W0 : (z == 1) ? W1 : (z == 2) ? W2 : W3;
    unsigned short* dst = Wt + (size_t)z * 1048576;
    const int tx = tid & 31, ty = tid >> 5;  // 32 x 8
#pragma unroll
    for (int i = 0; i < 32; i += 8)
      tile[ty + i][tx] = W[(size_t)(k0 + ty + i) * 1024 + n0 + tx];
    __syncthreads();
#pragma unroll
    for (int i = 0; i < 32; i += 8)
      dst[(size_t)(n0 + ty + i) * 1024 + k0 + tx] = f2bf(tile[tx][ty + i]);
  }
}

// ---------------------------------------------------------------- GEMM 128^2 (R10-proven row-major)
// MODE 0: O-proj. out fp32 [8192][1024], bias b0. grid 512 flat.
// MODE 1: merged QKV. Bt = [3072][1024], out = QKV bf16 base (Q,K scatter to
//         [b,h,s,hd]; Q scaled by QSCALE); mb==2 (V) written TRANSPOSED to
//         vtg[bh][hd][s] as 8B ushort4 (4 consecutive s). grid 1536 flat.
// XCD-chunked decode: XCD x owns by in [8x, 8x+8); bx-major, by-inner.
template <int MODE>
__global__ __launch_bounds__(256) void gemm128(const unsigned short* __restrict__ A,
                                               const unsigned short* __restrict__ Bt,
                                               const float* __restrict__ b0,
                                               const float* __restrict__ b1,
                                               const float* __restrict__ b2,
                                               void* __restrict__ out,
                                               unsigned short* __restrict__ vtg) {
  constexpr int Kd = 1024;
  __shared__ unsigned short sm[128 * 32 + 32 * 128];
  unsigned short* As = sm;
  unsigned short* Bs = sm + 128 * 32;
  auto lds3 = (__attribute__((address_space(3))) char*)sm;

  const int tid = threadIdx.x;
  const int wave = tid >> 6, lane = tid & 63, quad = lane >> 4, l16 = lane & 15;
  const int wm = wave >> 1, wn = wave & 1;

  const int id = blockIdx.x;
  const int nid = id >> 3;
  const int by = (id & 7) * 8 + (nid & 7);
  const int bx = nid >> 3;
  const int bm = by * 128, bn = bx * 128;

  f32x4 acc[4][4] = {};

  for (int k0 = 0; k0 < Kd; k0 += 32) {
#pragma unroll
    for (int j = 0; j < 2; ++j) {
      int i = (wave * 2 + j) * 64 + lane;  // 16B-chunk index 0..511
      const unsigned short* ga = A + (size_t)(bm + (i >> 2)) * Kd + k0 + (i & 3) * 8;
      __builtin_amdgcn_global_load_lds(
          (const __attribute__((address_space(1))) void*)ga,
          (__attribute__((address_space(3))) void*)(lds3 + (size_t)(wave * 2 + j) * 1024),
          16, 0, 0);
      const unsigned short* gb = Bt + (size_t)(bn + (i >> 2)) * Kd + k0 + (i & 3) * 8;
      __builtin_amdgcn_global_load_lds(
          (const __attribute__((address_space(1))) void*)gb,
          (__attribute__((address_space(3))) void*)(lds3 + 8192 + (size_t)(wave * 2 + j) * 1024),
          16, 0, 0);
    }
    __syncthreads();

    bf16x8 af[4], bfv[4];
#pragma unroll
    for (int i = 0; i < 4; ++i)
      af[i] = *(const bf16x8*)(As + (wm * 64 + i * 16 + l16) * 32 + quad * 8);
#pragma unroll
    for (int n = 0; n < 4; ++n)
      bfv[n] = *(const bf16x8*)(Bs + (wn * 64 + n * 16 + l16) * 32 + quad * 8);
#pragma unroll
    for (int i = 0; i < 4; ++i)
#pragma unroll
      for (int n = 0; n < 4; ++n)
        acc[i][n] = MFMA16(af[i], bfv[n], acc[i][n]);
    __syncthreads();
  }

  // epilogue: C/D layout col=lane&15, row=quad*4+reg
  const int mb = bn >> 10;  // matrix id for MODE 1 (block never straddles: 1024%128==0)
  const float* bias = (MODE == 0) ? b0 : (mb == 0 ? b0 : (mb == 1 ? b1 : b2));
  const float scale = (MODE == 1 && mb == 0) ? QSCALE : 1.0f;
  unsigned short* oq = (MODE == 1) ? ((unsigned short*)out + (size_t)mb * 8388608u) : nullptr;

#pragma unroll
  for (int i = 0; i < 4; ++i) {
    const int row0 = bm + wm * 64 + i * 16 + quad * 4;
#pragma unroll
    for (int n = 0; n < 4; ++n) {
      const int col = bn + wn * 64 + n * 16 + l16;
      const int cl = col & 1023;
      const float bv = bias[cl];
      if (MODE == 1 && mb == 2) {
        // V^T: vtg[(b*16+h)][hd][s], 4 consecutive s per thread -> 8B store
        const int h = cl >> 6, hd = cl & 63;
        const int b = row0 >> 11, s0v = row0 & 2047;
        ushort4 pk;
        pk.x = f2bf(acc[i][n][0] + bv);
        pk.y = f2bf(acc[i][n][1] + bv);
        pk.z = f2bf(acc[i][n][2] + bv);
        pk.w = f2bf(acc[i][n][3] + bv);
        *(ushort4*)(vtg + (size_t)(b * 16 + h) * 131072 + (size_t)hd * 2048 + s0v) = pk;
      } else {
#pragma unroll
        for (int r = 0; r < 4; ++r) {
          float v = (acc[i][n][r] + bv) * scale;
          if (MODE == 0) {
            ((float*)out)[(size_t)(row0 + r) * 1024 + col] = v;
          } else {
            int rr = row0 + r;
            int b = rr >> 11, s = rr & 2047;
            int h = cl >> 6, hd = cl & 63;
            oq[((size_t)(b * 16 + h) * 2048 + s) * 64 + hd] = f2bf(v);
          }
        }
      }
    }
  }
}

// ---------------------------------------------------------------- flash attention
// Q pre-scaled. 512 flat blocks; block = (b,h) x 256 q-rows; wave = 64 q-rows
// (4 subtiles). XCD-grouped decode: bh = (id&7)*8 + ((id>>3)>>3) so all 8
// q-blocks of a head (and 8 whole heads) land on one XCD -> K/Vt L2-resident
// (proven R2/R3: FETCH 139 -> 25.7 MB). No setprio: lockstep loop (m190/R3).
// S^T = K(A) @ Q^T(B): C-layout puts col=l16=qrow, so each lane's 16 exp2'd
// scores (keys quad*4+r per subtile) form PV A-frags directly under the key
// permutation sigma(q*8+j) = st*32 + (j>>2)*16 + q*4 + (j&3); V B-frags use
// the same sigma (two contiguous b64 chunks from the Vt tile). No P in LDS.
__global__ __launch_bounds__(256, 2) void attn_kernel(const unsigned short* __restrict__ Q,
                                                      const unsigned short* __restrict__ K,
                                                      const unsigned short* __restrict__ Vt,
                                                      unsigned short* __restrict__ ctx) {
  const int tid = threadIdx.x;
  const int wave = tid >> 6, lane = tid & 63, quad = lane >> 4, l16 = lane & 15;

  const int id = blockIdx.x;
  const int bh = (id & 7) * 8 + ((id >> 3) >> 3);  // 8 heads per XCD
  const int qx = (id >> 3) & 7;

  // stride 72 ushorts = 36 dwords == 4 mod 32 -> conflict-free-ish frag reads
  // double buffer: [buf][Ks 64*72 | Vts 64*72]
  __shared__ unsigned short sm[2][2 * 64 * 72];

  const size_t hb = (size_t)bh * 131072;
  const int q0 = qx * 256 + wave * 64;

  // Q B-frags: B[k=hd][n=qrow]: lane l16 = qrow, k = quad*8+j (+32*st)
  bf16x8 qf[4][2];
#pragma unroll
  for (int qt = 0; qt < 4; ++qt)
#pragma unroll
    for (int st = 0; st < 2; ++st)
      qf[qt][st] = *(const bf16x8*)(Q + hb + (size_t)(q0 + qt * 16 + l16) * 64 + st * 32 + quad * 8);

  f32x4 o[4][4] = {};
  float lacc[4] = {0.f, 0.f, 0.f, 0.f};

  // staging: 4 x 16B chunks/thread (2 K rows-of-keys + 2 Vt rows-of-hd)
  const int c0 = tid, c1 = tid + 256;
  const unsigned short* gK0 = K + hb + (size_t)(c0 >> 3) * 64 + (c0 & 7) * 8;
  const unsigned short* gK1 = K + hb + (size_t)(c1 >> 3) * 64 + (c1 & 7) * 8;
  const unsigned short* gV0 = Vt + hb + (size_t)(c0 >> 3) * 2048 + (c0 & 7) * 8;
  const unsigned short* gV1 = Vt + hb + (size_t)(c1 >> 3) * 2048 + (c1 & 7) * 8;
  const int sKo = (c0 >> 3) * 72 + (c0 & 7) * 8;
  const int sKo1 = (c1 >> 3) * 72 + (c1 & 7) * 8;

  u32x4 pk0 = *(const u32x4*)gK0, pk1 = *(const u32x4*)gK1;
  u32x4 pv0 = *(const u32x4*)gV0, pv1 = *(const u32x4*)gV1;
  {
    unsigned short* s0b = sm[0];
    *(u32x4*)(s0b + sKo) = pk0; *(u32x4*)(s0b + sKo1) = pk1;
    *(u32x4*)(s0b + 4608 + sKo) = pv0; *(u32x4*)(s0b + 4608 + sKo1) = pv1;
  }
  __syncthreads();

  for (int kb = 0; kb < 2048; kb += 64) {
    const int cur = (kb >> 6) & 1;
    const bool more = (kb + 64) < 2048;
    if (more) {
      pk0 = *(const u32x4*)(gK0 + (size_t)(kb + 64) * 64);
      pk1 = *(const u32x4*)(gK1 + (size_t)(kb + 64) * 64);
      pv0 = *(const u32x4*)(gV0 + kb + 64);
      pv1 = *(const u32x4*)(gV1 + kb + 64);
    }
    const unsigned short* Ks = sm[cur];
    const unsigned short* Vts = sm[cur] + 4608;

    // K A-frags: A[m=key][k=hd]: lane l16 = key (per subtile ks), contiguous hd
    bf16x8 kf[4][2];
#pragma unroll
    for (int ks = 0; ks < 4; ++ks)
#pragma unroll
      for (int st = 0; st < 2; ++st)
        kf[ks][st] = *(const bf16x8*)(Ks + (ks * 16 + l16) * 72 + st * 32 + quad * 8);

    // V B-frags under sigma: two b64 chunks (keys st*32+quad*4+{0..3}, +16)
    bf16x8 vf[4][2];
#pragma unroll
    for (int os = 0; os < 4; ++os)
#pragma unroll
      for (int st = 0; st < 2; ++st) {
        const unsigned short* rb = Vts + (os * 16 + l16) * 72 + st * 32 + quad * 4;
        bf16x4 a = *(const bf16x4*)rb;
        bf16x4 b2 = *(const bf16x4*)(rb + 16);
        vf[os][st] = __builtin_shufflevector(a, b2, 0, 1, 2, 3, 4, 5, 6, 7);
      }

#pragma unroll
    for (int qt = 0; qt < 4; ++qt) {
      // S^T tiles: rows = keys (quad*4+r), cols = qrows (l16)
      f32x4 sc[4];
#pragma unroll
      for (int ks = 0; ks < 4; ++ks) {
        f32x4 a = {0.f, 0.f, 0.f, 0.f};
        a = MFMA16(kf[ks][0], qf[qt][0], a);
        a = MFMA16(kf[ks][1], qf[qt][1], a);
        sc[ks] = a;
      }
      // exp2 -> P A-frags in-register; per-lane l partials (all for qrow l16)
      bf16x8 pf[2];
      float ls = 0.f;
#pragma unroll
      for (int ks = 0; ks < 4; ++ks)
#pragma unroll
        for (int r = 0; r < 4; ++r) {
          float p = __builtin_amdgcn_exp2f(sc[ks][r]);
          ls += p;
          pf[ks >> 1][(ks & 1) * 4 + r] = (__bf16)p;
        }
      lacc[qt] += ls;
#pragma unroll
      for (int st = 0; st < 2; ++st)
#pragma unroll
        for (int os = 0; os < 4; ++os)
          o[qt][os] = MFMA16(pf[st], vf[os][st], o[qt][os]);
    }

    if (more) {
      unsigned short* sn = sm[cur ^ 1];
      *(u32x4*)(sn + sKo) = pk0; *(u32x4*)(sn + sKo1) = pk1;
      *(u32x4*)(sn + 4608 + sKo) = pv0; *(u32x4*)(sn + 4608 + sKo1) = pv1;
    }
    __syncthreads();
  }

  // finalize: reduce l across quads (lane's l16 = qrow), redistribute to
  // C-layout rows (quad*4+r), normalize, store.
  const int b = bh >> 4, h = bh & 15;
#pragma unroll
  for (int qt = 0; qt < 4; ++qt) {
    float l = lacc[qt];
    l += __shfl_xor(l, 16, 64);
    l += __shfl_xor(l, 32, 64);
#pragma unroll
    for (int r = 0; r < 4; ++r) {
      float lr = __shfl(l, quad * 4 + r, 16);
      float inv = 1.0f / lr;
      int s = q0 + qt * 16 + quad * 4 + r;
#pragma unroll
      for (int os = 0; os < 4; ++os)
        ctx[((size_t)(b * 2048 + s)) * 1024 + h * 64 + os * 16 + l16] = f2bf(o[qt][os][r] * inv);
    }
  }
}

// ---------------------------------------------------------------- launch
extern "C" void kernel_launch(void* const* d_in, const int* in_sizes, int n_in,
                              void* d_out, int out_size, void* d_ws, size_t ws_size,
                              hipStream_t stream) {
  const float* x  = (const float*)d_in[0];
  const float* Wq = (const float*)d_in[1];
  const float* bq = (const float*)d_in[2];
  const float* Wk = (const float*)d_in[3];
  const float* bk = (const float*)d_in[4];
  const float* Wv = (const float*)d_in[5];
  const float* bv = (const float*)d_in[6];
  const float* Wo = (const float*)d_in[7];
  const float* bo = (const float*)d_in[8];

  unsigned short* ws = (unsigned short*)d_ws;
  unsigned short* xb    = ws;                    // 8388608  A input; attn out after QKV
  unsigned short* Wtall = ws + 8388608;          // 4*1048576 (Wq^T|Wk^T|Wv^T|Wo^T)
  unsigned short* Wot   = Wtall + 3145728;
  unsigned short* Qb    = Wtall + 4194304;       // 8388608  [bh][s][hd], pre-scaled
  unsigned short* Kb    = Qb + 8388608;          // 8388608  [bh][s][hd]
  unsigned short* VtG   = Kb + 8388608;          // 8388608  [bh][hd][s] (written by QKV epilogue)
  unsigned short* Cb    = xb;                    // alias: xb dead after QKV GEMM

  prep_kernel<<<dim3(12288), 256, 0, stream>>>(x, xb, Wq, Wk, Wv, Wo, Wtall);
  gemm128<1><<<dim3(1536), 256, 0, stream>>>(xb, Wtall, bq, bk, bv, Qb, VtG);
  attn_kernel<<<dim3(512), 256, 0, stream>>>(Qb, Kb, VtG, Cb);
  gemm128<0><<<dim3(512), 256, 0, stream>>>(Cb, Wot, bo, nullptr, nullptr, d_out, nullptr);
}

// Round 15
// 260.907 us; speedup vs baseline: 1.1435x; 1.0374x over previous
//
#include <hip/hip_runtime.h>
#include <stdint.h>

// B=4, S=2048, D=1024, H=16, Hd=64, M=8192.
// Pipeline: prep (cast x + W^T casts, one dispatch); merged QKV GEMM (128^2
// row-major, BK=64, XCD-chunked; Q pre-scaled by log2e/8; V written
// TRANSPOSED [bh][hd][s] from the epilogue); flash attn (S^T = K@Q^T
// key-permutation trick); O-projection GEMM (BK=64, fp32 out).
// Ledger: R2 XCD decode cuts attn FETCH 139->24.6MB. R3 setprio hurts
// lockstep attn. R4-R8: 256^2 QKV pinned ~80-95us at any schedule.
// R10: V^T fused into QKV epilogue -> 268.6 (best). R11: frag-major LDS
// breaks global coalescing with global_load_lds (85->112us) — row-major +
// 8-way conflict is the local optimum. R12: merged prep neutral (270.7).
// R13/R14: cooperative megakernel abandoned — absmax 0.2597656 IDENTICAL
// with and without agent-scope fences => deterministic failure (grid.sync
// unreliable under this harness's graph-captured cooperative launch).
// R15: R12 base + BK=64 in both GEMMs: four 128x32 subtiles per buffer
// (A-lo|A-hi|B-lo|B-hi, 32KB LDS) -> same frag layout/coalescing, HALF the
// __syncthreads drains (m233: stage+drain+barrier ~72% of 2-phase cost).

typedef float f32x4 __attribute__((ext_vector_type(4)));
typedef __bf16 bf16x4 __attribute__((ext_vector_type(4)));
typedef __bf16 bf16x8 __attribute__((ext_vector_type(8)));
typedef uint32_t u32x4 __attribute__((ext_vector_type(4)));

#define MFMA16(a, b, c) __builtin_amdgcn_mfma_f32_16x16x32_bf16((a), (b), (c), 0, 0, 0)

// Q pre-scale: log2(e)/8 so attn does p = exp2(Q'.K) = e^{QK/8} (unnormalized)
#define QSCALE 0.1803368801111204f

__device__ __forceinline__ unsigned short f2bf(float f) {
  union { float f; uint32_t u; } c; c.f = f;
  uint32_t u = c.u;
  return (unsigned short)((u + 0x7fffu + ((u >> 16) & 1u)) >> 16);  // RNE
}

// ---------------------------------------------------------------- prep
// blocks [0,8192): cast x (fp32 -> bf16, float4/ushort4 vectorized).
// blocks [8192,12288): W^T casts — 4 weights [k][n] fp32 -> Wt [n][k] bf16,
// 32x32 LDS tile per block (1024 blocks per weight).
__global__ __launch_bounds__(256) void prep_kernel(const float* __restrict__ x,
                                                   unsigned short* __restrict__ xb,
                                                   const float* __restrict__ W0,
                                                   const float* __restrict__ W1,
                                                   const float* __restrict__ W2,
                                                   const float* __restrict__ W3,
                                                   unsigned short* __restrict__ Wt) {
  __shared__ float tile[32][33];
  const int id = blockIdx.x;
  const int tid = threadIdx.x;
  if (id < 8192) {
    int i = id * 256 + tid;  // exactly 2097152 float4s
    float4 v = ((const float4*)x)[i];
    ushort4 o;
    o.x = f2bf(v.x); o.y = f2bf(v.y); o.z = f2bf(v.z); o.w = f2bf(v.w);
    ((ushort4*)xb)[i] = o;
  } else {
    const int t = id - 8192;
    const int z = t >> 10, r = t & 1023;
    const int k0 = (r >> 5) * 32, n0 = (r & 31) * 32;
    const float* W = (z == 0) ? W0 : (z == 1) ? W1 : (z == 2) ? W2 : W3;
    unsigned short* dst = Wt + (size_t)z * 1048576;
    const int tx = tid & 31, ty = tid >> 5;  // 32 x 8
#pragma unroll
    for (int i = 0; i < 32; i += 8)
      tile[ty + i][tx] = W[(size_t)(k0 + ty + i) * 1024 + n0 + tx];
    __syncthreads();
#pragma unroll
    for (int i = 0; i < 32; i += 8)
      dst[(size_t)(n0 + ty + i) * 1024 + k0 + tx] = f2bf(tile[tx][ty + i]);
  }
}

// ---------------------------------------------------------------- GEMM 128^2, BK=64
// MODE 0: O-proj. out fp32 [8192][1024], bias b0. grid 512 flat.
// MODE 1: merged QKV. Bt = [3072][1024], out = QKV bf16 base (Q,K scatter to
//         [b,h,s,hd]; Q scaled by QSCALE); mb==2 (V) written TRANSPOSED to
//         vtg[bh][hd][s] as 8B ushort4 (4 consecutive s). grid 1536 flat.
// XCD-chunked decode: XCD x owns by in [8x, 8x+8); bx-major, by-inner.
// LDS = four 128x32 row-major subtiles (A-lo|A-hi|B-lo|B-hi, 32KB): keeps
// R10's proven frag layout + coalescing; one __syncthreads pair per 64 K
// (drain amortized over 32 MFMAs instead of 16 — m233).
template <int MODE>
__global__ __launch_bounds__(256) void gemm128(const unsigned short* __restrict__ A,
                                               const unsigned short* __restrict__ Bt,
                                               const float* __restrict__ b0,
                                               const float* __restrict__ b1,
                                               const float* __restrict__ b2,
                                               void* __restrict__ out,
                                               unsigned short* __restrict__ vtg) {
  constexpr int Kd = 1024;
  __shared__ unsigned short sm[16384];  // 32 KB: Alo 4096 | Ahi 4096 | Blo 4096 | Bhi 4096 (ushorts)
  auto lds3 = (__attribute__((address_space(3))) char*)sm;

  const int tid = threadIdx.x;
  const int wave = tid >> 6, lane = tid & 63, quad = lane >> 4, l16 = lane & 15;
  const int wm = wave >> 1, wn = wave & 1;

  const int id = blockIdx.x;
  const int nid = id >> 3;
  const int by = (id & 7) * 8 + (nid & 7);
  const int bx = nid >> 3;
  const int bm = by * 128, bn = bx * 128;

  f32x4 acc[4][4] = {};

  for (int k0 = 0; k0 < Kd; k0 += 64) {
#pragma unroll
    for (int j = 0; j < 2; ++j) {
      int i = (wave * 2 + j) * 64 + lane;  // 16B-chunk 0..511 of a 128x32 subtile
      const int lo = (wave * 2 + j) * 1024;  // wave-uniform LDS byte base
      const unsigned short* ga = A + (size_t)(bm + (i >> 2)) * Kd + k0 + (i & 3) * 8;
      __builtin_amdgcn_global_load_lds(
          (const __attribute__((address_space(1))) void*)ga,
          (__attribute__((address_space(3))) void*)(lds3 + lo), 16, 0, 0);
      __builtin_amdgcn_global_load_lds(
          (const __attribute__((address_space(1))) void*)(ga + 32),
          (__attribute__((address_space(3))) void*)(lds3 + 8192 + lo), 16, 0, 0);
      const unsigned short* gb = Bt + (size_t)(bn + (i >> 2)) * Kd + k0 + (i & 3) * 8;
      __builtin_amdgcn_global_load_lds(
          (const __attribute__((address_space(1))) void*)gb,
          (__attribute__((address_space(3))) void*)(lds3 + 16384 + lo), 16, 0, 0);
      __builtin_amdgcn_global_load_lds(
          (const __attribute__((address_space(1))) void*)(gb + 32),
          (__attribute__((address_space(3))) void*)(lds3 + 24576 + lo), 16, 0, 0);
    }
    __syncthreads();

    bf16x8 af[4], bfv[4];
    // k-lo half (subtiles at ushort offsets: A-lo 0, B-lo 8192)
#pragma unroll
    for (int i = 0; i < 4; ++i)
      af[i] = *(const bf16x8*)(sm + (wm * 64 + i * 16 + l16) * 32 + quad * 8);
#pragma unroll
    for (int n = 0; n < 4; ++n)
      bfv[n] = *(const bf16x8*)(sm + 8192 + (wn * 64 + n * 16 + l16) * 32 + quad * 8);
#pragma unroll
    for (int i = 0; i < 4; ++i)
#pragma unroll
      for (int n = 0; n < 4; ++n)
        acc[i][n] = MFMA16(af[i], bfv[n], acc[i][n]);
    // k-hi half (A-hi 4096, B-hi 12288)
#pragma unroll
    for (int i = 0; i < 4; ++i)
      af[i] = *(const bf16x8*)(sm + 4096 + (wm * 64 + i * 16 + l16) * 32 + quad * 8);
#pragma unroll
    for (int n = 0; n < 4; ++n)
      bfv[n] = *(const bf16x8*)(sm + 12288 + (wn * 64 + n * 16 + l16) * 32 + quad * 8);
#pragma unroll
    for (int i = 0; i < 4; ++i)
#pragma unroll
      for (int n = 0; n < 4; ++n)
        acc[i][n] = MFMA16(af[i], bfv[n], acc[i][n]);
    __syncthreads();
  }

  // epilogue: C/D layout col=lane&15, row=quad*4+reg
  const int mb = bn >> 10;  // matrix id for MODE 1 (block never straddles: 1024%128==0)
  const float* bias = (MODE == 0) ? b0 : (mb == 0 ? b0 : (mb == 1 ? b1 : b2));
  const float scale = (MODE == 1 && mb == 0) ? QSCALE : 1.0f;
  unsigned short* oq = (MODE == 1) ? ((unsigned short*)out + (size_t)mb * 8388608u) : nullptr;

#pragma unroll
  for (int i = 0; i < 4; ++i) {
    const int row0 = bm + wm * 64 + i * 16 + quad * 4;
#pragma unroll
    for (int n = 0; n < 4; ++n) {
      const int col = bn + wn * 64 + n * 16 + l16;
      const int cl = col & 1023;
      const float bv = bias[cl];
      if (MODE == 1 && mb == 2) {
        // V^T: vtg[(b*16+h)][hd][s], 4 consecutive s per thread -> 8B store
        const int h = cl >> 6, hd = cl & 63;
        const int b = row0 >> 11, s0v = row0 & 2047;
        ushort4 pk;
        pk.x = f2bf(acc[i][n][0] + bv);
        pk.y = f2bf(acc[i][n][1] + bv);
        pk.z = f2bf(acc[i][n][2] + bv);
        pk.w = f2bf(acc[i][n][3] + bv);
        *(ushort4*)(vtg + (size_t)(b * 16 + h) * 131072 + (size_t)hd * 2048 + s0v) = pk;
      } else {
#pragma unroll
        for (int r = 0; r < 4; ++r) {
          float v = (acc[i][n][r] + bv) * scale;
          if (MODE == 0) {
            ((float*)out)[(size_t)(row0 + r) * 1024 + col] = v;
          } else {
            int rr = row0 + r;
            int b = rr >> 11, s = rr & 2047;
            int h = cl >> 6, hd = cl & 63;
            oq[((size_t)(b * 16 + h) * 2048 + s) * 64 + hd] = f2bf(v);
          }
        }
      }
    }
  }
}

// ---------------------------------------------------------------- flash attention
// Q pre-scaled. 512 flat blocks; block = (b,h) x 256 q-rows; wave = 64 q-rows
// (4 subtiles). XCD-grouped decode: bh = (id&7)*8 + ((id>>3)>>3) so all 8
// q-blocks of a head (and 8 whole heads) land on one XCD -> K/Vt L2-resident
// (proven R2/R3: FETCH 139 -> 25.7 MB). No setprio: lockstep loop (m190/R3).
// S^T = K(A) @ Q^T(B): C-layout puts col=l16=qrow, so each lane's 16 exp2'd
// scores (keys quad*4+r per subtile) form PV A-frags directly under the key
// permutation sigma(q*8+j) = st*32 + (j>>2)*16 + q*4 + (j&3); V B-frags use
// the same sigma (two contiguous b64 chunks from the Vt tile). No P in LDS.
__global__ __launch_bounds__(256, 2) void attn_kernel(const unsigned short* __restrict__ Q,
                                                      const unsigned short* __restrict__ K,
                                                      const unsigned short* __restrict__ Vt,
                                                      unsigned short* __restrict__ ctx) {
  const int tid = threadIdx.x;
  const int wave = tid >> 6, lane = tid & 63, quad = lane >> 4, l16 = lane & 15;

  const int id = blockIdx.x;
  const int bh = (id & 7) * 8 + ((id >> 3) >> 3);  // 8 heads per XCD
  const int qx = (id >> 3) & 7;

  // stride 72 ushorts = 36 dwords == 4 mod 32 -> conflict-free-ish frag reads
  // double buffer: [buf][Ks 64*72 | Vts 64*72]
  __shared__ unsigned short sm[2][2 * 64 * 72];

  const size_t hb = (size_t)bh * 131072;
  const int q0 = qx * 256 + wave * 64;

  // Q B-frags: B[k=hd][n=qrow]: lane l16 = qrow, k = quad*8+j (+32*st)
  bf16x8 qf[4][2];
#pragma unroll
  for (int qt = 0; qt < 4; ++qt)
#pragma unroll
    for (int st = 0; st < 2; ++st)
      qf[qt][st] = *(const bf16x8*)(Q + hb + (size_t)(q0 + qt * 16 + l16) * 64 + st * 32 + quad * 8);

  f32x4 o[4][4] = {};
  float lacc[4] = {0.f, 0.f, 0.f, 0.f};

  // staging: 4 x 16B chunks/thread (2 K rows-of-keys + 2 Vt rows-of-hd)
  const int c0 = tid, c1 = tid + 256;
  const unsigned short* gK0 = K + hb + (size_t)(c0 >> 3) * 64 + (c0 & 7) * 8;
  const unsigned short* gK1 = K + hb + (size_t)(c1 >> 3) * 64 + (c1 & 7) * 8;
  const unsigned short* gV0 = Vt + hb + (size_t)(c0 >> 3) * 2048 + (c0 & 7) * 8;
  const unsigned short* gV1 = Vt + hb + (size_t)(c1 >> 3) * 2048 + (c1 & 7) * 8;
  const int sKo = (c0 >> 3) * 72 + (c0 & 7) * 8;
  const int sKo1 = (c1 >> 3) * 72 + (c1 & 7) * 8;

  u32x4 pk0 = *(const u32x4*)gK0, pk1 = *(const u32x4*)gK1;
  u32x4 pv0 = *(const u32x4*)gV0, pv1 = *(const u32x4*)gV1;
  {
    unsigned short* s0b = sm[0];
    *(u32x4*)(s0b + sKo) = pk0; *(u32x4*)(s0b + sKo1) = pk1;
    *(u32x4*)(s0b + 4608 + sKo) = pv0; *(u32x4*)(s0b + 4608 + sKo1) = pv1;
  }
  __syncthreads();

  for (int kb = 0; kb < 2048; kb += 64) {
    const int cur = (kb >> 6) & 1;
    const bool more = (kb + 64) < 2048;
    if (more) {
      pk0 = *(const u32x4*)(gK0 + (size_t)(kb + 64) * 64);
      pk1 = *(const u32x4*)(gK1 + (size_t)(kb + 64) * 64);
      pv0 = *(const u32x4*)(gV0 + kb + 64);
      pv1 = *(const u32x4*)(gV1 + kb + 64);
    }
    const unsigned short* Ks = sm[cur];
    const unsigned short* Vts = sm[cur] + 4608;

    // K A-frags: A[m=key][k=hd]: lane l16 = key (per subtile ks), contiguous hd
    bf16x8 kf[4][2];
#pragma unroll
    for (int ks = 0; ks < 4; ++ks)
#pragma unroll
      for (int st = 0; st < 2; ++st)
        kf[ks][st] = *(const bf16x8*)(Ks + (ks * 16 + l16) * 72 + st * 32 + quad * 8);

    // V B-frags under sigma: two b64 chunks (keys st*32+quad*4+{0..3}, +16)
    bf16x8 vf[4][2];
#pragma unroll
    for (int os = 0; os < 4; ++os)
#pragma unroll
      for (int st = 0; st < 2; ++st) {
        const unsigned short* rb = Vts + (os * 16 + l16) * 72 + st * 32 + quad * 4;
        bf16x4 a = *(const bf16x4*)rb;
        bf16x4 b2 = *(const bf16x4*)(rb + 16);
        vf[os][st] = __builtin_shufflevector(a, b2, 0, 1, 2, 3, 4, 5, 6, 7);
      }

#pragma unroll
    for (int qt = 0; qt < 4; ++qt) {
      // S^T tiles: rows = keys (quad*4+r), cols = qrows (l16)
      f32x4 sc[4];
#pragma unroll
      for (int ks = 0; ks < 4; ++ks) {
        f32x4 a = {0.f, 0.f, 0.f, 0.f};
        a = MFMA16(kf[ks][0], qf[qt][0], a);
        a = MFMA16(kf[ks][1], qf[qt][1], a);
        sc[ks] = a;
      }
      // exp2 -> P A-frags in-register; per-lane l partials (all for qrow l16)
      bf16x8 pf[2];
      float ls = 0.f;
#pragma unroll
      for (int ks = 0; ks < 4; ++ks)
#pragma unroll
        for (int r = 0; r < 4; ++r) {
          float p = __builtin_amdgcn_exp2f(sc[ks][r]);
          ls += p;
          pf[ks >> 1][(ks & 1) * 4 + r] = (__bf16)p;
        }
      lacc[qt] += ls;
#pragma unroll
      for (int st = 0; st < 2; ++st)
#pragma unroll
        for (int os = 0; os < 4; ++os)
          o[qt][os] = MFMA16(pf[st], vf[os][st], o[qt][os]);
    }

    if (more) {
      unsigned short* sn = sm[cur ^ 1];
      *(u32x4*)(sn + sKo) = pk0; *(u32x4*)(sn + sKo1) = pk1;
      *(u32x4*)(sn + 4608 + sKo) = pv0; *(u32x4*)(sn + 4608 + sKo1) = pv1;
    }
    __syncthreads();
  }

  // finalize: reduce l across quads (lane's l16 = qrow), redistribute to
  // C-layout rows (quad*4+r), normalize, store.
  const int b = bh >> 4, h = bh & 15;
#pragma unroll
  for (int qt = 0; qt < 4; ++qt) {
    float l = lacc[qt];
    l += __shfl_xor(l, 16, 64);
    l += __shfl_xor(l, 32, 64);
#pragma unroll
    for (int r = 0; r < 4; ++r) {
      float lr = __shfl(l, quad * 4 + r, 16);
      float inv = 1.0f / lr;
      int s = q0 + qt * 16 + quad * 4 + r;
#pragma unroll
      for (int os = 0; os < 4; ++os)
        ctx[((size_t)(b * 2048 + s)) * 1024 + h * 64 + os * 16 + l16] = f2bf(o[qt][os][r] * inv);
    }
  }
}

// ---------------------------------------------------------------- launch
extern "C" void kernel_launch(void* const* d_in, const int* in_sizes, int n_in,
                              void* d_out, int out_size, void* d_ws, size_t ws_size,
                              hipStream_t stream) {
  const float* x  = (const float*)d_in[0];
  const float* Wq = (const float*)d_in[1];
  const float* bq = (const float*)d_in[2];
  const float* Wk = (const float*)d_in[3];
  const float* bk = (const float*)d_in[4];
  const float* Wv = (const float*)d_in[5];
  const float* bv = (const float*)d_in[6];
  const float* Wo = (const float*)d_in[7];
  const float* bo = (const float*)d_in[8];

  unsigned short* ws = (unsigned short*)d_ws;
  unsigned short* xb    = ws;                    // 8388608  A input; attn out after QKV
  unsigned short* Wtall = ws + 8388608;          // 4*1048576 (Wq^T|Wk^T|Wv^T|Wo^T)
  unsigned short* Wot   = Wtall + 3145728;
  unsigned short* Qb    = Wtall + 4194304;       // 8388608  [bh][s][hd], pre-scaled
  unsigned short* Kb    = Qb + 8388608;          // 8388608  [bh][s][hd]
  unsigned short* VtG   = Kb + 8388608;          // 8388608  [bh][hd][s] (written by QKV epilogue)
  unsigned short* Cb    = xb;                    // alias: xb dead after QKV GEMM

  prep_kernel<<<dim3(12288), 256, 0, stream>>>(x, xb, Wq, Wk, Wv, Wo, Wtall);
  gemm128<1><<<dim3(1536), 256, 0, stream>>>(xb, Wtall, bq, bk, bv, Qb, VtG);
  attn_kernel<<<dim3(512), 256, 0, stream>>>(Qb, Kb, VtG, Cb);
  gemm128<0><<<dim3(512), 256, 0, stream>>>(Cb, Wot, bo, nullptr, nullptr, d_out, nullptr);
}

// Round 16
// 257.647 us; speedup vs baseline: 1.1580x; 1.0127x over previous
//
#include <hip/hip_runtime.h>
#include <stdint.h>

// B=4, S=2048, D=1024, H=16, Hd=64, M=8192.
// Pipeline: prep (cast x + W^T casts, one dispatch); merged QKV GEMM (128^2
// row-major, BK=128, XCD-chunked; Q pre-scaled by log2e/8; V written
// TRANSPOSED [bh][hd][s] from the epilogue); flash attn (S^T = K@Q^T
// key-permutation trick); O-projection GEMM (BK=128, fp32 out).
// Ledger: R2 XCD decode cuts attn FETCH 139->24.6MB. R3 setprio hurts
// lockstep attn. R4-R8: 256^2 QKV pinned ~80-95us at any schedule.
// R10: V^T fused into QKV epilogue -> 268.6. R11: frag-major LDS breaks
// global coalescing with global_load_lds — row-major + 8-way conflict is
// the local optimum. R13/R14: cooperative megakernel abandoned
// (deterministic absmax 0.26 regardless of fences; grid.sync unreliable
// under graph-captured cooperative launch in this harness).
// R15: BK=32->64 (drain amortized over 32 MFMAs): QKV 96.5->92.1, total
// 270.7->260.9 (best). m233 mechanism confirmed live.
// R16: BK=64->128 (8 subtiles, 64KB LDS, 8 K-iters, drain per 64 MFMAs).
// Occupancy-safe: regs bind at 2 blocks/CU (188 unified); 64KB LDS still
// allows 2. Frag layout/coalescing byte-identical.

typedef float f32x4 __attribute__((ext_vector_type(4)));
typedef __bf16 bf16x4 __attribute__((ext_vector_type(4)));
typedef __bf16 bf16x8 __attribute__((ext_vector_type(8)));
typedef uint32_t u32x4 __attribute__((ext_vector_type(4)));

#define MFMA16(a, b, c) __builtin_amdgcn_mfma_f32_16x16x32_bf16((a), (b), (c), 0, 0, 0)

// Q pre-scale: log2(e)/8 so attn does p = exp2(Q'.K) = e^{QK/8} (unnormalized)
#define QSCALE 0.1803368801111204f

__device__ __forceinline__ unsigned short f2bf(float f) {
  union { float f; uint32_t u; } c; c.f = f;
  uint32_t u = c.u;
  return (unsigned short)((u + 0x7fffu + ((u >> 16) & 1u)) >> 16);  // RNE
}

// ---------------------------------------------------------------- prep
// blocks [0,8192): cast x (fp32 -> bf16, float4/ushort4 vectorized).
// blocks [8192,12288): W^T casts — 4 weights [k][n] fp32 -> Wt [n][k] bf16,
// 32x32 LDS tile per block (1024 blocks per weight).
__global__ __launch_bounds__(256) void prep_kernel(const float* __restrict__ x,
                                                   unsigned short* __restrict__ xb,
                                                   const float* __restrict__ W0,
                                                   const float* __restrict__ W1,
                                                   const float* __restrict__ W2,
                                                   const float* __restrict__ W3,
                                                   unsigned short* __restrict__ Wt) {
  __shared__ float tile[32][33];
  const int id = blockIdx.x;
  const int tid = threadIdx.x;
  if (id < 8192) {
    int i = id * 256 + tid;  // exactly 2097152 float4s
    float4 v = ((const float4*)x)[i];
    ushort4 o;
    o.x = f2bf(v.x); o.y = f2bf(v.y); o.z = f2bf(v.z); o.w = f2bf(v.w);
    ((ushort4*)xb)[i] = o;
  } else {
    const int t = id - 8192;
    const int z = t >> 10, r = t & 1023;
    const int k0 = (r >> 5) * 32, n0 = (r & 31) * 32;
    const float* W = (z == 0) ? W0 : (z == 1) ? W1 : (z == 2) ? W2 : W3;
    unsigned short* dst = Wt + (size_t)z * 1048576;
    const int tx = tid & 31, ty = tid >> 5;  // 32 x 8
#pragma unroll
    for (int i = 0; i < 32; i += 8)
      tile[ty + i][tx] = W[(size_t)(k0 + ty + i) * 1024 + n0 + tx];
    __syncthreads();
#pragma unroll
    for (int i = 0; i < 32; i += 8)
      dst[(size_t)(n0 + ty + i) * 1024 + k0 + tx] = f2bf(tile[tx][ty + i]);
  }
}

// ---------------------------------------------------------------- GEMM 128^2, BK=128
// MODE 0: O-proj. out fp32 [8192][1024], bias b0. grid 512 flat.
// MODE 1: merged QKV. Bt = [3072][1024], out = QKV bf16 base (Q,K scatter to
//         [b,h,s,hd]; Q scaled by QSCALE); mb==2 (V) written TRANSPOSED to
//         vtg[bh][hd][s] as 8B ushort4 (4 consecutive s). grid 1536 flat.
// XCD-chunked decode: XCD x owns by in [8x, 8x+8); bx-major, by-inner.
// LDS = eight 128x32 row-major subtiles (A k0..k3 | B k0..k3, 64KB): keeps
// the proven frag layout + coalescing; one __syncthreads pair per 128 K
// (drain amortized over 64 MFMAs — m233 ladder, R15 confirmed live).
template <int MODE>
__global__ __launch_bounds__(256) void gemm128(const unsigned short* __restrict__ A,
                                               const unsigned short* __restrict__ Bt,
                                               const float* __restrict__ b0,
                                               const float* __restrict__ b1,
                                               const float* __restrict__ b2,
                                               void* __restrict__ out,
                                               unsigned short* __restrict__ vtg) {
  constexpr int Kd = 1024;
  __shared__ unsigned short sm[32768];  // 64 KB: A[4 subtiles 4096 each] | B[4 subtiles], ushorts
  auto lds3 = (__attribute__((address_space(3))) char*)sm;

  const int tid = threadIdx.x;
  const int wave = tid >> 6, lane = tid & 63, quad = lane >> 4, l16 = lane & 15;
  const int wm = wave >> 1, wn = wave & 1;

  const int id = blockIdx.x;
  const int nid = id >> 3;
  const int by = (id & 7) * 8 + (nid & 7);
  const int bx = nid >> 3;
  const int bm = by * 128, bn = bx * 128;

  f32x4 acc[4][4] = {};

  for (int k0 = 0; k0 < Kd; k0 += 128) {
#pragma unroll
    for (int j = 0; j < 2; ++j) {
      int i = (wave * 2 + j) * 64 + lane;  // 16B-chunk 0..511 of a 128x32 subtile
      const int lo = (wave * 2 + j) * 1024;  // wave-uniform LDS byte base
      const unsigned short* ga = A + (size_t)(bm + (i >> 2)) * Kd + k0 + (i & 3) * 8;
      const unsigned short* gb = Bt + (size_t)(bn + (i >> 2)) * Kd + k0 + (i & 3) * 8;
#pragma unroll
      for (int s = 0; s < 4; ++s) {
        __builtin_amdgcn_global_load_lds(
            (const __attribute__((address_space(1))) void*)(ga + s * 32),
            (__attribute__((address_space(3))) void*)(lds3 + s * 8192 + lo), 16, 0, 0);
        __builtin_amdgcn_global_load_lds(
            (const __attribute__((address_space(1))) void*)(gb + s * 32),
            (__attribute__((address_space(3))) void*)(lds3 + 32768 + s * 8192 + lo), 16, 0, 0);
      }
    }
    __syncthreads();

    bf16x8 af[4], bfv[4];
#pragma unroll
    for (int s = 0; s < 4; ++s) {
      // subtile s: A at ushort offset s*4096, B at 16384 + s*4096
#pragma unroll
      for (int i = 0; i < 4; ++i)
        af[i] = *(const bf16x8*)(sm + s * 4096 + (wm * 64 + i * 16 + l16) * 32 + quad * 8);
#pragma unroll
      for (int n = 0; n < 4; ++n)
        bfv[n] = *(const bf16x8*)(sm + 16384 + s * 4096 + (wn * 64 + n * 16 + l16) * 32 + quad * 8);
#pragma unroll
      for (int i = 0; i < 4; ++i)
#pragma unroll
        for (int n = 0; n < 4; ++n)
          acc[i][n] = MFMA16(af[i], bfv[n], acc[i][n]);
    }
    __syncthreads();
  }

  // epilogue: C/D layout col=lane&15, row=quad*4+reg
  const int mb = bn >> 10;  // matrix id for MODE 1 (block never straddles: 1024%128==0)
  const float* bias = (MODE == 0) ? b0 : (mb == 0 ? b0 : (mb == 1 ? b1 : b2));
  const float scale = (MODE == 1 && mb == 0) ? QSCALE : 1.0f;
  unsigned short* oq = (MODE == 1) ? ((unsigned short*)out + (size_t)mb * 8388608u) : nullptr;

#pragma unroll
  for (int i = 0; i < 4; ++i) {
    const int row0 = bm + wm * 64 + i * 16 + quad * 4;
#pragma unroll
    for (int n = 0; n < 4; ++n) {
      const int col = bn + wn * 64 + n * 16 + l16;
      const int cl = col & 1023;
      const float bv = bias[cl];
      if (MODE == 1 && mb == 2) {
        // V^T: vtg[(b*16+h)][hd][s], 4 consecutive s per thread -> 8B store
        const int h = cl >> 6, hd = cl & 63;
        const int b = row0 >> 11, s0v = row0 & 2047;
        ushort4 pk;
        pk.x = f2bf(acc[i][n][0] + bv);
        pk.y = f2bf(acc[i][n][1] + bv);
        pk.z = f2bf(acc[i][n][2] + bv);
        pk.w = f2bf(acc[i][n][3] + bv);
        *(ushort4*)(vtg + (size_t)(b * 16 + h) * 131072 + (size_t)hd * 2048 + s0v) = pk;
      } else {
#pragma unroll
        for (int r = 0; r < 4; ++r) {
          float v = (acc[i][n][r] + bv) * scale;
          if (MODE == 0) {
            ((float*)out)[(size_t)(row0 + r) * 1024 + col] = v;
          } else {
            int rr = row0 + r;
            int b = rr >> 11, s = rr & 2047;
            int h = cl >> 6, hd = cl & 63;
            oq[((size_t)(b * 16 + h) * 2048 + s) * 64 + hd] = f2bf(v);
          }
        }
      }
    }
  }
}

// ---------------------------------------------------------------- flash attention
// Q pre-scaled. 512 flat blocks; block = (b,h) x 256 q-rows; wave = 64 q-rows
// (4 subtiles). XCD-grouped decode: bh = (id&7)*8 + ((id>>3)>>3) so all 8
// q-blocks of a head (and 8 whole heads) land on one XCD -> K/Vt L2-resident
// (proven R2/R3: FETCH 139 -> 25.7 MB). No setprio: lockstep loop (m190/R3).
// S^T = K(A) @ Q^T(B): C-layout puts col=l16=qrow, so each lane's 16 exp2'd
// scores (keys quad*4+r per subtile) form PV A-frags directly under the key
// permutation sigma(q*8+j) = st*32 + (j>>2)*16 + q*4 + (j&3); V B-frags use
// the same sigma (two contiguous b64 chunks from the Vt tile). No P in LDS.
__global__ __launch_bounds__(256, 2) void attn_kernel(const unsigned short* __restrict__ Q,
                                                      const unsigned short* __restrict__ K,
                                                      const unsigned short* __restrict__ Vt,
                                                      unsigned short* __restrict__ ctx) {
  const int tid = threadIdx.x;
  const int wave = tid >> 6, lane = tid & 63, quad = lane >> 4, l16 = lane & 15;

  const int id = blockIdx.x;
  const int bh = (id & 7) * 8 + ((id >> 3) >> 3);  // 8 heads per XCD
  const int qx = (id >> 3) & 7;

  // stride 72 ushorts = 36 dwords == 4 mod 32 -> conflict-free-ish frag reads
  // double buffer: [buf][Ks 64*72 | Vts 64*72]
  __shared__ unsigned short sm[2][2 * 64 * 72];

  const size_t hb = (size_t)bh * 131072;
  const int q0 = qx * 256 + wave * 64;

  // Q B-frags: B[k=hd][n=qrow]: lane l16 = qrow, k = quad*8+j (+32*st)
  bf16x8 qf[4][2];
#pragma unroll
  for (int qt = 0; qt < 4; ++qt)
#pragma unroll
    for (int st = 0; st < 2; ++st)
      qf[qt][st] = *(const bf16x8*)(Q + hb + (size_t)(q0 + qt * 16 + l16) * 64 + st * 32 + quad * 8);

  f32x4 o[4][4] = {};
  float lacc[4] = {0.f, 0.f, 0.f, 0.f};

  // staging: 4 x 16B chunks/thread (2 K rows-of-keys + 2 Vt rows-of-hd)
  const int c0 = tid, c1 = tid + 256;
  const unsigned short* gK0 = K + hb + (size_t)(c0 >> 3) * 64 + (c0 & 7) * 8;
  const unsigned short* gK1 = K + hb + (size_t)(c1 >> 3) * 64 + (c1 & 7) * 8;
  const unsigned short* gV0 = Vt + hb + (size_t)(c0 >> 3) * 2048 + (c0 & 7) * 8;
  const unsigned short* gV1 = Vt + hb + (size_t)(c1 >> 3) * 2048 + (c1 & 7) * 8;
  const int sKo = (c0 >> 3) * 72 + (c0 & 7) * 8;
  const int sKo1 = (c1 >> 3) * 72 + (c1 & 7) * 8;

  u32x4 pk0 = *(const u32x4*)gK0, pk1 = *(const u32x4*)gK1;
  u32x4 pv0 = *(const u32x4*)gV0, pv1 = *(const u32x4*)gV1;
  {
    unsigned short* s0b = sm[0];
    *(u32x4*)(s0b + sKo) = pk0; *(u32x4*)(s0b + sKo1) = pk1;
    *(u32x4*)(s0b + 4608 + sKo) = pv0; *(u32x4*)(s0b + 4608 + sKo1) = pv1;
  }
  __syncthreads();

  for (int kb = 0; kb < 2048; kb += 64) {
    const int cur = (kb >> 6) & 1;
    const bool more = (kb + 64) < 2048;
    if (more) {
      pk0 = *(const u32x4*)(gK0 + (size_t)(kb + 64) * 64);
      pk1 = *(const u32x4*)(gK1 + (size_t)(kb + 64) * 64);
      pv0 = *(const u32x4*)(gV0 + kb + 64);
      pv1 = *(const u32x4*)(gV1 + kb + 64);
    }
    const unsigned short* Ks = sm[cur];
    const unsigned short* Vts = sm[cur] + 4608;

    // K A-frags: A[m=key][k=hd]: lane l16 = key (per subtile ks), contiguous hd
    bf16x8 kf[4][2];
#pragma unroll
    for (int ks = 0; ks < 4; ++ks)
#pragma unroll
      for (int st = 0; st < 2; ++st)
        kf[ks][st] = *(const bf16x8*)(Ks + (ks * 16 + l16) * 72 + st * 32 + quad * 8);

    // V B-frags under sigma: two b64 chunks (keys st*32+quad*4+{0..3}, +16)
    bf16x8 vf[4][2];
#pragma unroll
    for (int os = 0; os < 4; ++os)
#pragma unroll
      for (int st = 0; st < 2; ++st) {
        const unsigned short* rb = Vts + (os * 16 + l16) * 72 + st * 32 + quad * 4;
        bf16x4 a = *(const bf16x4*)rb;
        bf16x4 b2 = *(const bf16x4*)(rb + 16);
        vf[os][st] = __builtin_shufflevector(a, b2, 0, 1, 2, 3, 4, 5, 6, 7);
      }

#pragma unroll
    for (int qt = 0; qt < 4; ++qt) {
      // S^T tiles: rows = keys (quad*4+r), cols = qrows (l16)
      f32x4 sc[4];
#pragma unroll
      for (int ks = 0; ks < 4; ++ks) {
        f32x4 a = {0.f, 0.f, 0.f, 0.f};
        a = MFMA16(kf[ks][0], qf[qt][0], a);
        a = MFMA16(kf[ks][1], qf[qt][1], a);
        sc[ks] = a;
      }
      // exp2 -> P A-frags in-register; per-lane l partials (all for qrow l16)
      bf16x8 pf[2];
      float ls = 0.f;
#pragma unroll
      for (int ks = 0; ks < 4; ++ks)
#pragma unroll
        for (int r = 0; r < 4; ++r) {
          float p = __builtin_amdgcn_exp2f(sc[ks][r]);
          ls += p;
          pf[ks >> 1][(ks & 1) * 4 + r] = (__bf16)p;
        }
      lacc[qt] += ls;
#pragma unroll
      for (int st = 0; st < 2; ++st)
#pragma unroll
        for (int os = 0; os < 4; ++os)
          o[qt][os] = MFMA16(pf[st], vf[os][st], o[qt][os]);
    }

    if (more) {
      unsigned short* sn = sm[cur ^ 1];
      *(u32x4*)(sn + sKo) = pk0; *(u32x4*)(sn + sKo1) = pk1;
      *(u32x4*)(sn + 4608 + sKo) = pv0; *(u32x4*)(sn + 4608 + sKo1) = pv1;
    }
    __syncthreads();
  }

  // finalize: reduce l across quads (lane's l16 = qrow), redistribute to
  // C-layout rows (quad*4+r), normalize, store.
  const int b = bh >> 4, h = bh & 15;
#pragma unroll
  for (int qt = 0; qt < 4; ++qt) {
    float l = lacc[qt];
    l += __shfl_xor(l, 16, 64);
    l += __shfl_xor(l, 32, 64);
#pragma unroll
    for (int r = 0; r < 4; ++r) {
      float lr = __shfl(l, quad * 4 + r, 16);
      float inv = 1.0f / lr;
      int s = q0 + qt * 16 + quad * 4 + r;
#pragma unroll
      for (int os = 0; os < 4; ++os)
        ctx[((size_t)(b * 2048 + s)) * 1024 + h * 64 + os * 16 + l16] = f2bf(o[qt][os][r] * inv);
    }
  }
}

// ---------------------------------------------------------------- launch
extern "C" void kernel_launch(void* const* d_in, const int* in_sizes, int n_in,
                              void* d_out, int out_size, void* d_ws, size_t ws_size,
                              hipStream_t stream) {
  const float* x  = (const float*)d_in[0];
  const float* Wq = (const float*)d_in[1];
  const float* bq = (const float*)d_in[2];
  const float* Wk = (const float*)d_in[3];
  const float* bk = (const float*)d_in[4];
  const float* Wv = (const float*)d_in[5];
  const float* bv = (const float*)d_in[6];
  const float* Wo = (const float*)d_in[7];
  const float* bo = (const float*)d_in[8];

  unsigned short* ws = (unsigned short*)d_ws;
  unsigned short* xb    = ws;                    // 8388608  A input; attn out after QKV
  unsigned short* Wtall = ws + 8388608;          // 4*1048576 (Wq^T|Wk^T|Wv^T|Wo^T)
  unsigned short* Wot   = Wtall + 3145728;
  unsigned short* Qb    = Wtall + 4194304;       // 8388608  [bh][s][hd], pre-scaled
  unsigned short* Kb    = Qb + 8388608;          // 8388608  [bh][s][hd]
  unsigned short* VtG   = Kb + 8388608;          // 8388608  [bh][hd][s] (written by QKV epilogue)
  unsigned short* Cb    = xb;                    // alias: xb dead after QKV GEMM

  prep_kernel<<<dim3(12288), 256, 0, stream>>>(x, xb, Wq, Wk, Wv, Wo, Wtall);
  gemm128<1><<<dim3(1536), 256, 0, stream>>>(xb, Wtall, bq, bk, bv, Qb, VtG);
  attn_kernel<<<dim3(512), 256, 0, stream>>>(Qb, Kb, VtG, Cb);
  gemm128<0><<<dim3(512), 256, 0, stream>>>(Cb, Wot, bo, nullptr, nullptr, d_out, nullptr);
}